// Round 1
// baseline (42.088 us; speedup 1.0000x reference)
//
#include <hip/hip_runtime.h>

#define EPS 1e-8f
constexpr int Bn = 8192, Ln = 512, Kn = 4;

__global__ __launch_bounds__(256) void em_kernel(
    const float* __restrict__ windows,
    const float* __restrict__ noise,
    const float* __restrict__ init_centers,
    const float* __restrict__ init_scales,
    const float* __restrict__ init_weights,
    const float* __restrict__ prior_w_param,
    const float* __restrict__ log_weights,
    const float* __restrict__ blend_param,
    float* __restrict__ g_out,      // B*L*K
    float* __restrict__ p_out,      // B*K
    float* __restrict__ a_out,      // B*K
    float* __restrict__ b_out)      // B*K
{
    const int b    = blockIdx.x;
    const int tid  = threadIdx.x;
    const int wave = tid >> 6;
    const int lane = tid & 63;

    __shared__ float s_part[4][12];
    __shared__ float s_bc[4];

    const float* xrow = windows + (size_t)b * Ln;
    float x0 = xrow[tid];
    float x1 = xrow[tid + 256];

    // ---- pass A: mean / var(ddof=1) ----
    float s  = x0 + x1;
    float sq = x0 * x0 + x1 * x1;
    #pragma unroll
    for (int off = 32; off; off >>= 1) {
        s  += __shfl_xor(s,  off, 64);
        sq += __shfl_xor(sq, off, 64);
    }
    if (lane == 0) { s_part[wave][0] = s; s_part[wave][1] = sq; }
    __syncthreads();
    if (tid == 0) {
        float S = 0.f, SQ = 0.f;
        for (int w = 0; w < 4; ++w) { S += s_part[w][0]; SQ += s_part[w][1]; }
        float mean = S / (float)Ln;
        float var  = (SQ - S * S / (float)Ln) / (float)(Ln - 1);
        var = fmaxf(var, 0.f);
        s_bc[0] = mean; s_bc[1] = sqrtf(var); s_bc[2] = var;
    }
    __syncthreads();
    const float mean = s_bc[0], stdv = s_bc[1], var = s_bc[2];

    // ---- per-component constants (redundant per thread; K=4, cheap) ----
    float mu[Kn], inv_sig[Kn], logc[Kn];
    #pragma unroll
    for (int k = 0; k < Kn; ++k) {
        float m  = init_centers[k] * stdv + mean + noise[(size_t)b * Kn + k] * stdv * 0.01f;
        float sg = fabsf(init_scales[k]) * stdv;
        float is = 1.0f / (sg + EPS);
        mu[k]      = m;
        inv_sig[k] = is;
        logc[k]    = __logf((init_weights[k] + EPS) * is);
    }

    // ---- pass B: softmax responsibilities + weighted moments ----
    float s0[Kn] = {0,0,0,0}, s1[Kn] = {0,0,0,0}, s2[Kn] = {0,0,0,0};

    #pragma unroll
    for (int j = 0; j < 2; ++j) {
        int   l = tid + j * 256;
        float x = (j == 0) ? x0 : x1;
        float lm[Kn];
        float mx = -1e30f;
        #pragma unroll
        for (int k = 0; k < Kn; ++k) {
            float t = (x - mu[k]) * inv_sig[k];
            lm[k] = fmaf(t * t, -0.5f, logc[k]);
            mx = fmaxf(mx, lm[k]);
        }
        float e[Kn], sum = 0.f;
        #pragma unroll
        for (int k = 0; k < Kn; ++k) { e[k] = __expf(lm[k] - mx); sum += e[k]; }
        float inv = 1.0f / sum;
        float4 gv;
        gv.x = e[0] * inv; gv.y = e[1] * inv; gv.z = e[2] * inv; gv.w = e[3] * inv;
        reinterpret_cast<float4*>(g_out)[(size_t)b * Ln + l] = gv;

        float wl = __expf(log_weights[l]);
        float gk[Kn] = {gv.x, gv.y, gv.z, gv.w};
        #pragma unroll
        for (int k = 0; k < Kn; ++k) {
            float wg = gk[k] * wl;
            s0[k] += wg;
            s1[k] += wg * x;
            s2[k] += wg * x * x;
        }
    }

    // ---- reduce 12 accumulators: wave shfl, then LDS across 4 waves ----
    #pragma unroll
    for (int k = 0; k < Kn; ++k) {
        #pragma unroll
        for (int off = 32; off; off >>= 1) {
            s0[k] += __shfl_xor(s0[k], off, 64);
            s1[k] += __shfl_xor(s1[k], off, 64);
            s2[k] += __shfl_xor(s2[k], off, 64);
        }
    }
    if (lane == 0) {
        #pragma unroll
        for (int k = 0; k < Kn; ++k) {
            s_part[wave][k]     = s0[k];
            s_part[wave][4 + k] = s1[k];
            s_part[wave][8 + k] = s2[k];
        }
    }
    __syncthreads();

    if (tid == 0) {
        float prior_w = 1.0f / (1.0f + __expf(-prior_w_param[0]));
        float blender = 1.0f / (1.0f + __expf(-blend_param[0]));
        float S0[Kn], S1[Kn], S2[Kn], pk[Kn];
        float psum = 0.f;
        #pragma unroll
        for (int k = 0; k < Kn; ++k) {
            S0[k] = s_part[0][k]   + s_part[1][k]   + s_part[2][k]   + s_part[3][k];
            S1[k] = s_part[0][4+k] + s_part[1][4+k] + s_part[2][4+k] + s_part[3][4+k];
            S2[k] = s_part[0][8+k] + s_part[1][8+k] + s_part[2][8+k] + s_part[3][8+k];
            float sg = fmaxf(S0[k], EPS);
            pk[k] = sg + prior_w;
            psum += pk[k];
        }
        float invp = 1.0f / psum;
        #pragma unroll
        for (int k = 0; k < Kn; ++k) {
            float sg   = fmaxf(S0[k], EPS);
            float dmu  = S1[k] / sg;
            float av   = dmu * blender + mean * (1.0f - blender);
            float dvar = (S2[k] - 2.0f * av * S1[k] + av * av * S0[k]) / sg;
            float bv   = sqrtf(dvar * blender + var * (1.0f - blender) + EPS);
            p_out[(size_t)b * Kn + k] = pk[k] * invp;
            a_out[(size_t)b * Kn + k] = av;
            b_out[(size_t)b * Kn + k] = bv;
        }
    }
}

extern "C" void kernel_launch(void* const* d_in, const int* in_sizes, int n_in,
                              void* d_out, int out_size, void* d_ws, size_t ws_size,
                              hipStream_t stream) {
    const float* windows       = (const float*)d_in[0];
    const float* noise         = (const float*)d_in[1];
    const float* init_centers  = (const float*)d_in[2];
    const float* init_scales   = (const float*)d_in[3];
    const float* init_weights  = (const float*)d_in[4];
    const float* prior_w_param = (const float*)d_in[5];
    const float* log_weights   = (const float*)d_in[6];
    const float* blend_param   = (const float*)d_in[7];

    float* out = (float*)d_out;
    const size_t G  = (size_t)Bn * Ln * Kn;   // 16,777,216
    const size_t BK = (size_t)Bn * Kn;        // 32,768
    float* g_out = out;
    float* p_out = out + G;
    float* a_out = out + G + BK;
    float* b_out = out + G + 2 * BK;

    em_kernel<<<dim3(Bn), dim3(256), 0, stream>>>(
        windows, noise, init_centers, init_scales, init_weights,
        prior_w_param, log_weights, blend_param,
        g_out, p_out, a_out, b_out);
}

// Round 2
// 27.355 us; speedup vs baseline: 1.5386x; 1.5386x over previous
//
#include <hip/hip_runtime.h>

#define EPS 1e-8f
constexpr int Bn = 8192, Ln = 512, Kn = 4;
constexpr int EPT = Ln / 64;   // 8 elements per lane

__global__ __launch_bounds__(256, 8) void em_kernel(
    const float* __restrict__ windows,
    const float* __restrict__ noise,
    const float* __restrict__ init_centers,
    const float* __restrict__ init_scales,
    const float* __restrict__ init_weights,
    const float* __restrict__ prior_w_param,
    const float* __restrict__ log_weights,
    const float* __restrict__ blend_param,
    float* __restrict__ g_out,      // B*L*K
    float* __restrict__ p_out,      // B*K
    float* __restrict__ a_out,      // B*K
    float* __restrict__ b_out)      // B*K
{
    const int wave = threadIdx.x >> 6;
    const int lane = threadIdx.x & 63;
    const int row  = blockIdx.x * 4 + wave;   // one wave per row, no inter-wave deps

    const float* xrow = windows + (size_t)row * Ln;

    // ---- load row into registers (coalesced: lane + 64*j) ----
    float x[EPT];
    #pragma unroll
    for (int j = 0; j < EPT; ++j) x[j] = xrow[lane + 64 * j];

    // ---- pass A: mean / var(ddof=1), wave-local butterfly ----
    float s = 0.f, sq = 0.f;
    #pragma unroll
    for (int j = 0; j < EPT; ++j) { s += x[j]; sq = fmaf(x[j], x[j], sq); }
    #pragma unroll
    for (int off = 32; off; off >>= 1) {
        s  += __shfl_xor(s,  off, 64);
        sq += __shfl_xor(sq, off, 64);
    }
    // all lanes now hold full sums — no broadcast needed
    const float mean = s * (1.0f / (float)Ln);
    float var = (sq - s * s * (1.0f / (float)Ln)) * (1.0f / (float)(Ln - 1));
    var = fmaxf(var, 0.f);
    const float stdv = sqrtf(var);

    // ---- per-component constants (uniform within wave) ----
    float mu[Kn], inv_sig[Kn], logc[Kn];
    #pragma unroll
    for (int k = 0; k < Kn; ++k) {
        float m  = fmaf(init_centers[k], stdv, mean)
                 + noise[(size_t)row * Kn + k] * stdv * 0.01f;
        float sg = fabsf(init_scales[k]) * stdv;
        float is = 1.0f / (sg + EPS);
        mu[k]      = m;
        inv_sig[k] = is;
        logc[k]    = __logf((init_weights[k] + EPS) * is);
    }

    // ---- pass B: softmax responsibilities + weighted moments ----
    float s0[Kn] = {0,0,0,0}, s1[Kn] = {0,0,0,0}, s2[Kn] = {0,0,0,0};

    #pragma unroll
    for (int j = 0; j < EPT; ++j) {
        const int l  = lane + 64 * j;
        const float xv = x[j];
        float lm[Kn];
        float mx = -1e30f;
        #pragma unroll
        for (int k = 0; k < Kn; ++k) {
            float t = (xv - mu[k]) * inv_sig[k];
            lm[k] = fmaf(t * t, -0.5f, logc[k]);
            mx = fmaxf(mx, lm[k]);
        }
        float e[Kn], sum = 0.f;
        #pragma unroll
        for (int k = 0; k < Kn; ++k) { e[k] = __expf(lm[k] - mx); sum += e[k]; }
        float inv = 1.0f / sum;
        float4 gv;
        gv.x = e[0] * inv; gv.y = e[1] * inv; gv.z = e[2] * inv; gv.w = e[3] * inv;
        reinterpret_cast<float4*>(g_out)[(size_t)row * Ln + l] = gv;

        float wl = __expf(log_weights[l]);
        float gk[Kn] = {gv.x, gv.y, gv.z, gv.w};
        #pragma unroll
        for (int k = 0; k < Kn; ++k) {
            float wg = gk[k] * wl;
            s0[k] += wg;
            s1[k] = fmaf(wg, xv, s1[k]);
            s2[k] = fmaf(wg * xv, xv, s2[k]);
        }
    }

    // ---- wave-local butterfly over 12 accumulators ----
    #pragma unroll
    for (int k = 0; k < Kn; ++k) {
        #pragma unroll
        for (int off = 32; off; off >>= 1) {
            s0[k] += __shfl_xor(s0[k], off, 64);
            s1[k] += __shfl_xor(s1[k], off, 64);
            s2[k] += __shfl_xor(s2[k], off, 64);
        }
    }

    // ---- epilogue: lane 0 of each wave writes p, a, b ----
    if (lane == 0) {
        float prior_w = 1.0f / (1.0f + __expf(-prior_w_param[0]));
        float blender = 1.0f / (1.0f + __expf(-blend_param[0]));
        float pk[Kn];
        float psum = 0.f;
        #pragma unroll
        for (int k = 0; k < Kn; ++k) {
            float sg = fmaxf(s0[k], EPS);
            pk[k] = sg + prior_w;
            psum += pk[k];
        }
        float invp = 1.0f / psum;
        #pragma unroll
        for (int k = 0; k < Kn; ++k) {
            float sg   = fmaxf(s0[k], EPS);
            float dmu  = s1[k] / sg;
            float av   = dmu * blender + mean * (1.0f - blender);
            float dvar = (s2[k] - 2.0f * av * s1[k] + av * av * s0[k]) / sg;
            float bv   = sqrtf(dvar * blender + var * (1.0f - blender) + EPS);
            p_out[(size_t)row * Kn + k] = pk[k] * invp;
            a_out[(size_t)row * Kn + k] = av;
            b_out[(size_t)row * Kn + k] = bv;
        }
    }
}

extern "C" void kernel_launch(void* const* d_in, const int* in_sizes, int n_in,
                              void* d_out, int out_size, void* d_ws, size_t ws_size,
                              hipStream_t stream) {
    const float* windows       = (const float*)d_in[0];
    const float* noise         = (const float*)d_in[1];
    const float* init_centers  = (const float*)d_in[2];
    const float* init_scales   = (const float*)d_in[3];
    const float* init_weights  = (const float*)d_in[4];
    const float* prior_w_param = (const float*)d_in[5];
    const float* log_weights   = (const float*)d_in[6];
    const float* blend_param   = (const float*)d_in[7];

    float* out = (float*)d_out;
    const size_t G  = (size_t)Bn * Ln * Kn;   // 16,777,216
    const size_t BK = (size_t)Bn * Kn;        // 32,768
    float* g_out = out;
    float* p_out = out + G;
    float* a_out = out + G + BK;
    float* b_out = out + G + 2 * BK;

    em_kernel<<<dim3(Bn / 4), dim3(256), 0, stream>>>(
        windows, noise, init_centers, init_scales, init_weights,
        prior_w_param, log_weights, blend_param,
        g_out, p_out, a_out, b_out);
}